// Round 1
// baseline (46.792 us; speedup 1.0000x reference)
//
#include <hip/hip_runtime.h>

// Power-of-two per-tensor fixed-point scales
// ACT_SCALE = 2^-6, W_SCALE = 2^-7, bias_scale = 2^-13
__device__ __forceinline__ float fq(float x, float inv_s, float s) {
    float r = rintf(x * inv_s);                 // round half-to-even == jnp.round
    r = fminf(fmaxf(r, -128.0f), 127.0f);       // clamp to int8 range
    return r * s;
}

// 4 rows (of 10 floats) per thread: 160 B in via 10x float4, 48 B out via 3x float4.
__global__ __launch_bounds__(256) void dummy_linear_q_kernel(
        const float* __restrict__ x, const float* __restrict__ W,
        const float* __restrict__ b, float* __restrict__ out, int nthreads) {
    int t = blockIdx.x * blockDim.x + threadIdx.x;
    if (t >= nthreads) return;

    // Quantize weights + bias (uniform addresses -> scalar loads, L1-resident)
    float wq[3][10];
#pragma unroll
    for (int n = 0; n < 3; ++n)
#pragma unroll
        for (int k = 0; k < 10; ++k)
            wq[n][k] = fq(W[n * 10 + k], 128.0f, 1.0f / 128.0f);
    float bq[3];
#pragma unroll
    for (int n = 0; n < 3; ++n)
        bq[n] = fq(b[n], 8192.0f, 1.0f / 8192.0f);

    // Load 4 rows = 40 floats, vectorized
    float xr[40];
    const float4* xp = reinterpret_cast<const float4*>(x + (size_t)t * 40);
#pragma unroll
    for (int i = 0; i < 10; ++i) {
        float4 v = xp[i];
        xr[4 * i + 0] = v.x;
        xr[4 * i + 1] = v.y;
        xr[4 * i + 2] = v.z;
        xr[4 * i + 3] = v.w;
    }

    // Quantize activations once per element
#pragma unroll
    for (int i = 0; i < 40; ++i)
        xr[i] = fq(xr[i], 64.0f, 1.0f / 64.0f);

    // 4 rows x 3 outputs, K=10 dots
    float4 o[3];
    float oo[12];
#pragma unroll
    for (int r = 0; r < 4; ++r) {
#pragma unroll
        for (int n = 0; n < 3; ++n) {
            float acc = bq[n];
#pragma unroll
            for (int k = 0; k < 10; ++k)
                acc = fmaf(xr[r * 10 + k], wq[n][k], acc);
            oo[r * 3 + n] = acc;
        }
    }
#pragma unroll
    for (int i = 0; i < 3; ++i) {
        o[i].x = oo[4 * i + 0];
        o[i].y = oo[4 * i + 1];
        o[i].z = oo[4 * i + 2];
        o[i].w = oo[4 * i + 3];
    }
    float4* op = reinterpret_cast<float4*>(out + (size_t)t * 12);
#pragma unroll
    for (int i = 0; i < 3; ++i) op[i] = o[i];
}

// Scalar tail kernel (only launched if rows % 4 != 0 — not expected here).
__global__ void dummy_linear_q_tail(
        const float* __restrict__ x, const float* __restrict__ W,
        const float* __restrict__ b, float* __restrict__ out,
        int row_start, int nrows) {
    int r = row_start + blockIdx.x * blockDim.x + threadIdx.x;
    if (r >= nrows) return;
    float wq[3][10];
    for (int n = 0; n < 3; ++n)
        for (int k = 0; k < 10; ++k)
            wq[n][k] = fq(W[n * 10 + k], 128.0f, 1.0f / 128.0f);
    for (int n = 0; n < 3; ++n) {
        float acc = fq(b[n], 8192.0f, 1.0f / 8192.0f);
        for (int k = 0; k < 10; ++k)
            acc = fmaf(fq(x[(size_t)r * 10 + k], 64.0f, 1.0f / 64.0f), wq[n][k], acc);
        out[(size_t)r * 3 + n] = acc;
    }
}

extern "C" void kernel_launch(void* const* d_in, const int* in_sizes, int n_in,
                              void* d_out, int out_size, void* d_ws, size_t ws_size,
                              hipStream_t stream) {
    const float* x = (const float*)d_in[0];
    const float* W = (const float*)d_in[1];
    const float* b = (const float*)d_in[2];
    float* out = (float*)d_out;

    int B = in_sizes[0] / 10;          // 4194304 rows
    int nthreads = B / 4;              // 4 rows per thread
    if (nthreads > 0) {
        int block = 256;
        int grid = (nthreads + block - 1) / block;
        dummy_linear_q_kernel<<<grid, block, 0, stream>>>(x, W, b, out, nthreads);
    }
    int done = nthreads * 4;
    if (done < B) {
        int rem = B - done;
        dummy_linear_q_tail<<<(rem + 63) / 64, 64, 0, stream>>>(x, W, b, out, done, B);
    }
}

// Round 2
// 36.980 us; speedup vs baseline: 1.2653x; 1.2653x over previous
//
#include <hip/hip_runtime.h>

// Power-of-two per-tensor fixed-point scales
// ACT_SCALE = 2^-6, W_SCALE = 2^-7, bias_scale = 2^-13
__device__ __forceinline__ float fq(float x, float inv_s, float s) {
    float r = rintf(x * inv_s);                 // round half-to-even == jnp.round
    r = fminf(fmaxf(r, -128.0f), 127.0f);       // clamp to int8 range
    return r * s;
}

// Block = 256 threads, 4 rows/thread -> 1024 rows/block.
// Stage 40 KB of x into LDS with coalesced float4 loads, compute per-thread,
// stage 12 KB of output back through LDS, store coalesced.
__global__ __launch_bounds__(256) void dummy_linear_q_kernel(
        const float* __restrict__ x, const float* __restrict__ W,
        const float* __restrict__ b, float* __restrict__ out) {
    __shared__ float4 lds4[2560];               // 40 KB
    const int tid = threadIdx.x;

    // Quantize weights + bias (uniform addresses -> scalar loads, L1-resident)
    float wq[3][10];
#pragma unroll
    for (int n = 0; n < 3; ++n)
#pragma unroll
        for (int k = 0; k < 10; ++k)
            wq[n][k] = fq(W[n * 10 + k], 128.0f, 1.0f / 128.0f);
    float bq[3];
#pragma unroll
    for (int n = 0; n < 3; ++n)
        bq[n] = fq(b[n], 8192.0f, 1.0f / 8192.0f);

    // Coalesced stage-in: 2560 float4 per block, 10 per thread
    const float4* xg = reinterpret_cast<const float4*>(x) + (size_t)blockIdx.x * 2560;
#pragma unroll
    for (int j = 0; j < 10; ++j)
        lds4[j * 256 + tid] = xg[j * 256 + tid];
    __syncthreads();

    // Each thread: rows 4*tid .. 4*tid+3 within the block = 40 floats at lds4[tid*10]
    float xr[40];
    const float4* lp = lds4 + tid * 10;
#pragma unroll
    for (int i = 0; i < 10; ++i) {
        float4 v = lp[i];
        xr[4 * i + 0] = v.x;
        xr[4 * i + 1] = v.y;
        xr[4 * i + 2] = v.z;
        xr[4 * i + 3] = v.w;
    }

#pragma unroll
    for (int i = 0; i < 40; ++i)
        xr[i] = fq(xr[i], 64.0f, 1.0f / 64.0f);

    // 4 rows x 3 outputs, K=10 dots
    float oo[12];
#pragma unroll
    for (int r = 0; r < 4; ++r) {
#pragma unroll
        for (int n = 0; n < 3; ++n) {
            float acc = bq[n];
#pragma unroll
            for (int k = 0; k < 10; ++k)
                acc = fmaf(xr[r * 10 + k], wq[n][k], acc);
            oo[r * 3 + n] = acc;
        }
    }

    // Stage-out through LDS (reuse buffer), then coalesced float4 stores
    __syncthreads();
#pragma unroll
    for (int i = 0; i < 3; ++i) {
        float4 v;
        v.x = oo[4 * i + 0];
        v.y = oo[4 * i + 1];
        v.z = oo[4 * i + 2];
        v.w = oo[4 * i + 3];
        lds4[tid * 3 + i] = v;
    }
    __syncthreads();

    float4* og = reinterpret_cast<float4*>(out) + (size_t)blockIdx.x * 768;
#pragma unroll
    for (int j = 0; j < 3; ++j)
        og[j * 256 + tid] = lds4[j * 256 + tid];
}

// Scalar tail kernel (only launched if rows % 1024 != 0 — not expected here).
__global__ void dummy_linear_q_tail(
        const float* __restrict__ x, const float* __restrict__ W,
        const float* __restrict__ b, float* __restrict__ out,
        int row_start, int nrows) {
    int r = row_start + blockIdx.x * blockDim.x + threadIdx.x;
    if (r >= nrows) return;
    float wq[3][10];
    for (int n = 0; n < 3; ++n)
        for (int k = 0; k < 10; ++k)
            wq[n][k] = fq(W[n * 10 + k], 128.0f, 1.0f / 128.0f);
    for (int n = 0; n < 3; ++n) {
        float acc = fq(b[n], 8192.0f, 1.0f / 8192.0f);
        for (int k = 0; k < 10; ++k)
            acc = fmaf(fq(x[(size_t)r * 10 + k], 64.0f, 1.0f / 64.0f), wq[n][k], acc);
        out[(size_t)r * 3 + n] = acc;
    }
}

extern "C" void kernel_launch(void* const* d_in, const int* in_sizes, int n_in,
                              void* d_out, int out_size, void* d_ws, size_t ws_size,
                              hipStream_t stream) {
    const float* x = (const float*)d_in[0];
    const float* W = (const float*)d_in[1];
    const float* b = (const float*)d_in[2];
    float* out = (float*)d_out;

    int B = in_sizes[0] / 10;          // 4194304 rows
    int nblocks = B / 1024;            // 1024 rows per block
    if (nblocks > 0)
        dummy_linear_q_kernel<<<nblocks, 256, 0, stream>>>(x, W, b, out);
    int done = nblocks * 1024;
    if (done < B) {
        int rem = B - done;
        dummy_linear_q_tail<<<(rem + 63) / 64, 64, 0, stream>>>(x, W, b, out, done, B);
    }
}

// Round 4
// 36.256 us; speedup vs baseline: 1.2906x; 1.0200x over previous
//
#include <hip/hip_runtime.h>

typedef float f4 __attribute__((ext_vector_type(4)));  // native vec type for NT stores

// Power-of-two per-tensor fixed-point scales
// ACT_SCALE = 2^-6, W_SCALE = 2^-7, bias_scale = 2^-13
__device__ __forceinline__ float fq(float x, float inv_s, float s) {
    float r = rintf(x * inv_s);                 // round half-to-even == jnp.round
    r = fminf(fmaxf(r, -128.0f), 127.0f);       // clamp to int8 range
    return r * s;
}

// Block = 256 threads, 2 rows/thread -> 512 rows/block, 20 KB LDS.
// 20 KB/block -> 8 blocks/CU = 32 waves/CU (max occupancy) for MLP.
// Stage x in via coalesced float4, compute, stage out via LDS, nontemporal stores.
__global__ __launch_bounds__(256) void dummy_linear_q_kernel(
        const float* __restrict__ x, const float* __restrict__ W,
        const float* __restrict__ b, float* __restrict__ out) {
    __shared__ f4 lds4[1280];                   // 20 KB
    const int tid = threadIdx.x;

    // Quantize weights + bias (uniform addresses -> scalar loads, cached)
    float wq[3][10];
#pragma unroll
    for (int n = 0; n < 3; ++n)
#pragma unroll
        for (int k = 0; k < 10; ++k)
            wq[n][k] = fq(W[n * 10 + k], 128.0f, 1.0f / 128.0f);
    float bq[3];
#pragma unroll
    for (int n = 0; n < 3; ++n)
        bq[n] = fq(b[n], 8192.0f, 1.0f / 8192.0f);

    // Coalesced stage-in: 1280 float4 per block, 5 per thread
    const f4* xg = reinterpret_cast<const f4*>(x) + (size_t)blockIdx.x * 1280;
#pragma unroll
    for (int j = 0; j < 5; ++j)
        lds4[j * 256 + tid] = xg[j * 256 + tid];
    __syncthreads();

    // Each thread: rows 2*tid, 2*tid+1 = 20 floats at lds4[tid*5]
    float xr[20];
    const f4* lp = lds4 + tid * 5;
#pragma unroll
    for (int i = 0; i < 5; ++i) {
        f4 v = lp[i];
        xr[4 * i + 0] = v.x;
        xr[4 * i + 1] = v.y;
        xr[4 * i + 2] = v.z;
        xr[4 * i + 3] = v.w;
    }

#pragma unroll
    for (int i = 0; i < 20; ++i)
        xr[i] = fq(xr[i], 64.0f, 1.0f / 64.0f);

    // 2 rows x 3 outputs, K=10 dots
    float oo[6];
#pragma unroll
    for (int r = 0; r < 2; ++r) {
#pragma unroll
        for (int n = 0; n < 3; ++n) {
            float acc = bq[n];
#pragma unroll
            for (int k = 0; k < 10; ++k)
                acc = fmaf(xr[r * 10 + k], wq[n][k], acc);
            oo[r * 3 + n] = acc;
        }
    }

    // Stage-out through LDS (reuse buffer after barrier): 512*3 floats = 384 f4
    __syncthreads();
    float* lo = reinterpret_cast<float*>(lds4);
#pragma unroll
    for (int i = 0; i < 6; ++i)
        lo[tid * 6 + i] = oo[i];
    __syncthreads();

    // Coalesced nontemporal stores: 384 f4/block (thread<128 does a 2nd)
    f4* og = reinterpret_cast<f4*>(out) + (size_t)blockIdx.x * 384;
    __builtin_nontemporal_store(lds4[tid], &og[tid]);
    if (tid < 128)
        __builtin_nontemporal_store(lds4[256 + tid], &og[256 + tid]);
}

// Scalar tail kernel (only launched if rows % 512 != 0 — not expected here).
__global__ void dummy_linear_q_tail(
        const float* __restrict__ x, const float* __restrict__ W,
        const float* __restrict__ b, float* __restrict__ out,
        int row_start, int nrows) {
    int r = row_start + blockIdx.x * blockDim.x + threadIdx.x;
    if (r >= nrows) return;
    float wq[3][10];
    for (int n = 0; n < 3; ++n)
        for (int k = 0; k < 10; ++k)
            wq[n][k] = fq(W[n * 10 + k], 128.0f, 1.0f / 128.0f);
    for (int n = 0; n < 3; ++n) {
        float acc = fq(b[n], 8192.0f, 1.0f / 8192.0f);
        for (int k = 0; k < 10; ++k)
            acc = fmaf(fq(x[(size_t)r * 10 + k], 64.0f, 1.0f / 64.0f), wq[n][k], acc);
        out[(size_t)r * 3 + n] = acc;
    }
}

extern "C" void kernel_launch(void* const* d_in, const int* in_sizes, int n_in,
                              void* d_out, int out_size, void* d_ws, size_t ws_size,
                              hipStream_t stream) {
    const float* x = (const float*)d_in[0];
    const float* W = (const float*)d_in[1];
    const float* b = (const float*)d_in[2];
    float* out = (float*)d_out;

    int B = in_sizes[0] / 10;          // 4194304 rows
    int nblocks = B / 512;             // 512 rows per block
    if (nblocks > 0)
        dummy_linear_q_kernel<<<nblocks, 256, 0, stream>>>(x, W, b, out);
    int done = nblocks * 512;
    if (done < B) {
        int rem = B - done;
        dummy_linear_q_tail<<<(rem + 63) / 64, 64, 0, stream>>>(x, W, b, out, done, B);
    }
}